// Round 11
// baseline (117.967 us; speedup 1.0000x reference)
//
#include <hip/hip_runtime.h>

#define B_    32
#define S_    64
#define D_    8
#define NE_   512        // S_*D_
#define E_    150000
#define CAP   448        // compacted edges per bin (mean 293, ~9 sigma headroom)

#define SBLK  1024
#define BLKN  ((E_ + SBLK - 1) / SBLK)   // 147 scatter blocks
#define SLOTS 16                          // slots per (bin, block); Poisson(2), 9+ sigma
#define PBIN_PITCH (BLKN * SLOTS)         // 2352 ints per bin

// ws layout: cnt2D[NE_][BLKN] int | payload2D[NE_][BLKN*SLOTS] int
#define PAYLOAD_BYTE_OFF (NE_ * BLKN * 4)

typedef __attribute__((ext_vector_type(8)))  short  short8;   // 8 bf16 (4 VGPR)
typedef __attribute__((ext_vector_type(16))) float  float16;  // MFMA C/D (16 regs)

__device__ __forceinline__ unsigned short f2bf(float f) {
    union { float f; unsigned int u; } cv; cv.f = f;
    unsigned int u = cv.u;
    return (unsigned short)((u + 0x7fffu + ((u >> 16) & 1u)) >> 16);
}
__device__ __forceinline__ unsigned int pack2bf(float a, float b) {
    return (unsigned int)f2bf(a) | ((unsigned int)f2bf(b) << 16);
}

// ---------------- atomic-free binning scatter (unchanged from R10) ----------------
__global__ __launch_bounds__(SBLK)
void scatter_bin(const int* __restrict__ inc,
                 int* __restrict__ cnt2D,        // [bin][blk]
                 int* __restrict__ payload2D) {  // [bin][blk*SLOTS+slot]
    __shared__ int lcount[NE_];
    const int tid = threadIdx.x;

    for (int i = tid; i < NE_; i += SBLK) lcount[i] = 0;
    __syncthreads();

    const int e = blockIdx.x * SBLK + tid;
    int ei = -1, lp = 0, pl = 0;
    if (e < E_) {
        const int4 c = ((const int4*)inc)[e];   // c0=batch c1=node c2 c3
        ei = c.z * D_ + c.w;
        pl = (c.x << 16) | (c.y * S_ + c.z);
        lp = atomicAdd(&lcount[ei], 1);         // LDS atomic only
    }
    if (ei >= 0 && lp < SLOTS)
        payload2D[ei * PBIN_PITCH + blockIdx.x * SLOTS + lp] = pl;
    __syncthreads();
    if (tid < NE_)
        cnt2D[tid * BLKN + blockIdx.x] = min(lcount[tid], SLOTS);
}

// ---------------- MFMA main kernel, 4-barrier structure ----------------
// Layer0 (transposed): H^T = Wa(32x16) . X^T(16xn); Layer1: 2 chained K=16 MFMAs
// C/D layout: col = lane&31, row = (reg&3) + 8*(reg>>2) + 4*(lane>>5)
#define HLP 40   // Hl row pitch in shorts (80B rows: 16B-aligned, odd bank stride)

__global__ __launch_bounds__(512, 4)
void main_mfma(const float* __restrict__ nf,
               const float* __restrict__ iw0, const float* __restrict__ ib0,
               const float* __restrict__ iw1, const float* __restrict__ ib1,
               const float* __restrict__ ow0, const float* __restrict__ ob0,
               const float* __restrict__ ow1, const float* __restrict__ ob1,
               const int* __restrict__ cnt2D, const int* __restrict__ payload2D,
               float* __restrict__ out) {
    const int bid  = blockIdx.x;          // == eidx
    const int tid  = threadIdx.x;
    const int lane = tid & 63;
    const int wav  = tid >> 6;            // 0..7
    const int e32  = lane & 31;           // edge-in-tile / A-row
    const int q    = lane >> 5;           // k-half selector

    __shared__ float acc[32][33];
    __shared__ float hb[32][33];
    __shared__ float cnts[32];
    __shared__ float q0t[32 * 33];        // [k][o] transposed, pad 33
    __shared__ float q1t[32 * 17];        // [k][o] transposed, pad 17
    __shared__ float qb0s[32], qb1s[16];
    __shared__ float bias0s[32], bias1s[32];
    __shared__ int   scnt[160];           // inclusive scan of per-block counts
    __shared__ int   elist[CAP];          // compacted payload for this bin
    __shared__ unsigned short Hl[8][32 * HLP];   // per-wave H tile (bf16)

    // ---- phase A: issue ALL independent loads, wave0 does shfl-scan ----
    short8 aWa, aWb0, aWb1;
    {
        const float* wa = iw0 + (size_t)bid * 512 + e32 * 16 + q * 8;
        float4 u0 = ((const float4*)wa)[0], u1 = ((const float4*)wa)[1];
        unsigned int p[4] = { pack2bf(u0.x,u0.y), pack2bf(u0.z,u0.w),
                              pack2bf(u1.x,u1.y), pack2bf(u1.z,u1.w) };
        aWa = *(short8*)p;
    }
    {
        const float* wb = iw1 + (size_t)bid * 1024 + e32 * 32 + q * 8;
        float4 u0 = ((const float4*)wb)[0], u1 = ((const float4*)wb)[1];
        unsigned int p[4] = { pack2bf(u0.x,u0.y), pack2bf(u0.z,u0.w),
                              pack2bf(u1.x,u1.y), pack2bf(u1.z,u1.w) };
        aWb0 = *(short8*)p;
        const float* wb2 = wb + 16;
        float4 u2 = ((const float4*)wb2)[0], u3 = ((const float4*)wb2)[1];
        unsigned int p2[4] = { pack2bf(u2.x,u2.y), pack2bf(u2.z,u2.w),
                               pack2bf(u3.x,u3.y), pack2bf(u3.z,u3.w) };
        aWb1 = *(short8*)p2;
    }

    for (int i = tid; i < 1024; i += 512) {
        const int o = i >> 5, k = i & 31;
        q0t[k * 33 + o] = ow0[(size_t)bid * 1024 + i];
    }
    { const int o = tid >> 5, k = tid & 31;
      q1t[k * 17 + o] = ow1[(size_t)bid * 512 + tid]; }
    if (tid < 32)       { bias0s[tid] = ib0[bid * 32 + tid]; cnts[tid] = 0.f; }
    else if (tid < 64)  bias1s[tid - 32] = ib1[bid * 32 + (tid - 32)];
    else if (tid < 96)  qb0s[tid - 64] = ob0[bid * 32 + (tid - 64)];
    else if (tid < 112) qb1s[tid - 96] = ob1[bid * 16 + (tid - 96)];
    for (int i = tid; i < 32 * 33; i += 512) ((float*)acc)[i] = 0.f;

    if (wav == 0) {
        // inclusive scan of cnt2D[bid][0..146] entirely in wave 0 (no barriers)
        int base = 0;
        #pragma unroll
        for (int r = 0; r < 3; ++r) {
            const int idx = lane + 64 * r;
            int v = (idx < BLKN) ? cnt2D[bid * BLKN + idx] : 0;
            #pragma unroll
            for (int off = 1; off < 64; off <<= 1) {
                int y = __shfl_up(v, off, 64);
                if (lane >= off) v += y;
            }
            if (idx < BLKN + 13) scnt[idx] = base + v;  // write a bit past end, in-bounds of 160
            base += __shfl(v, 63, 64);
        }
    }
    __syncthreads();   // barrier 1: staging + scan table ready

    // per-lane bias registers (one-time broadcast LDS reads, loop-invariant)
    float bA[16], bB[16];
    #pragma unroll
    for (int r = 0; r < 16; ++r) {
        const int o_r = (r & 3) + 8 * (r >> 2) + 4 * q;
        bA[r] = bias0s[o_r];
        bB[r] = bias1s[o_r];
    }

    const int n = min(scnt[BLKN - 1], CAP);

    // ---- phase B: compact payload2D[bid] into LDS elist (coalesced reads) ----
    const int* Pb = payload2D + (size_t)bid * PBIN_PITCH;
    for (int pair = tid; pair < PBIN_PITCH; pair += 512) {
        const int blk = pair >> 4, s = pair & (SLOTS - 1);
        const int b0 = blk ? scnt[blk - 1] : 0;
        const int cc = scnt[blk] - b0;
        if (s < cc) {
            const int idx = b0 + s;
            if (idx < CAP) elist[idx] = Pb[pair];
        }
    }
    __syncthreads();   // barrier 2: elist ready

    const int ntiles = (n + 31) >> 5;
    unsigned short* hl = Hl[wav];

    for (int t = wav; t < ntiles; t += 8) {
        const int slot  = t * 32 + e32;
        const bool valid = slot < n;
        const int cs    = valid ? slot : (n - 1);   // clamped: masked later

        const int p   = elist[cs];
        const int b_e = p >> 16;
        const int row = p & 0xFFFF;

        short8 bX;
        {
            const float4* xp = (const float4*)(nf + (size_t)row * 16 + q * 8);
            float4 u0 = xp[0], u1 = xp[1];
            unsigned int pk[4] = { pack2bf(u0.x,u0.y), pack2bf(u0.z,u0.w),
                                   pack2bf(u1.x,u1.y), pack2bf(u1.z,u1.w) };
            bX = *(short8*)pk;
        }

        float16 c0;
        #pragma unroll
        for (int r = 0; r < 16; ++r) c0[r] = bA[r];
        c0 = __builtin_amdgcn_mfma_f32_32x32x16_bf16(aWa, bX, c0, 0, 0, 0);

        #pragma unroll
        for (int r = 0; r < 16; r += 2) {
            const int o_r = (r & 3) + 8 * (r >> 2) + 4 * q;
            const unsigned int pk = pack2bf(fmaxf(c0[r], 0.f), fmaxf(c0[r + 1], 0.f));
            *(unsigned int*)(hl + e32 * HLP + o_r) = pk;
        }

        short8 bH0 = *(const short8*)(hl + e32 * HLP + q * 8);        // k 0..15
        short8 bH1 = *(const short8*)(hl + e32 * HLP + 16 + q * 8);   // k 16..31
        float16 c1;
        #pragma unroll
        for (int r = 0; r < 16; ++r) c1[r] = bB[r];
        c1 = __builtin_amdgcn_mfma_f32_32x32x16_bf16(aWb0, bH0, c1, 0, 0, 0);
        c1 = __builtin_amdgcn_mfma_f32_32x32x16_bf16(aWb1, bH1, c1, 0, 0, 0);

        if (valid) {
            #pragma unroll
            for (int r = 0; r < 16; ++r) {
                const int o_r = (r & 3) + 8 * (r >> 2) + 4 * q;
                atomicAdd(&acc[b_e][o_r], fmaxf(c1[r], 0.f));
            }
            if (q == 0) atomicAdd(&cnts[b_e], 1.f);
        }
    }
    __syncthreads();   // barrier 3: acc ready

    // ---- mean + out layer 0: thread -> (b = tid>>4, outputs 2*(tid&15)..) ----
    {
        const int b  = tid >> 4;
        const int j  = tid & 15;
        const float cv  = cnts[b];
        const float inv = cv > 0.f ? 1.0f / cv : 0.0f;
        #pragma unroll
        for (int s = 0; s < 2; ++s) {
            const int oo = j * 2 + s;
            float d = 0.f;
            #pragma unroll
            for (int k = 0; k < 32; ++k) d = fmaf(q0t[k * 33 + oo], acc[b][k], d);
            hb[b][oo] = fmaxf(fmaf(d, inv, qb0s[oo]), 0.f);
        }
    }
    __syncthreads();   // barrier 4: hb ready

    // ---- out layer 1: thread -> (b = tid>>4, o = tid&15) ----
    {
        const int b = tid >> 4;
        const int o = tid & 15;
        float d = qb1s[o];
        #pragma unroll
        for (int k = 0; k < 32; ++k) d = fmaf(q1t[k * 17 + o], hb[b][k], d);
        out[((size_t)b * NE_ + bid) * 16 + o] = fmaxf(d, 0.f);
    }
}

extern "C" void kernel_launch(void* const* d_in, const int* in_sizes, int n_in,
                              void* d_out, int out_size, void* d_ws, size_t ws_size,
                              hipStream_t stream) {
    const float* nf  = (const float*)d_in[0];
    const float* iw0 = (const float*)d_in[1];
    const float* ib0 = (const float*)d_in[2];
    const float* iw1 = (const float*)d_in[3];
    const float* ib1 = (const float*)d_in[4];
    const float* ow0 = (const float*)d_in[5];
    const float* ob0 = (const float*)d_in[6];
    const float* ow1 = (const float*)d_in[7];
    const float* ob1 = (const float*)d_in[8];
    const int*   inc = (const int*)d_in[9];

    int* cnt2D     = (int*)d_ws;
    int* payload2D = (int*)((char*)d_ws + PAYLOAD_BYTE_OFF);

    scatter_bin<<<BLKN, SBLK, 0, stream>>>(inc, cnt2D, payload2D);
    main_mfma<<<NE_, 512, 0, stream>>>(nf, iw0, ib0, iw1, ib1, ow0, ob0, ow1, ob1,
                                       cnt2D, payload2D, (float*)d_out);
}